// Round 1
// baseline (1793.495 us; speedup 1.0000x reference)
//
#include <hip/hip_runtime.h>
#include <math.h>

#define NN 4096
#define DD 1024
#define NC 100
#define CP 128
#define NLAB 2048
#define NITER 30

// ---------------- normalize rows: En = E / max(||E_row||, 1e-12) ----------------
__global__ __launch_bounds__(256) void k_normalize(const float* __restrict__ E,
                                                   float* __restrict__ En) {
  int row = blockIdx.x;
  const float4* e4 = (const float4*)(E + (size_t)row * DD);
  float4* o4 = (float4*)(En + (size_t)row * DD);
  int t = threadIdx.x;
  float4 v = e4[t];
  float ss = v.x * v.x + v.y * v.y + v.z * v.z + v.w * v.w;
  __shared__ float red[4];
  int lane = t & 63, w = t >> 6;
#pragma unroll
  for (int off = 32; off; off >>= 1) ss += __shfl_xor(ss, off);
  if (lane == 0) red[w] = ss;
  __syncthreads();
  float tot = red[0] + red[1] + red[2] + red[3];
  float d = fmaxf(sqrtf(tot), 1e-12f);
  float4 o;
  o.x = v.x / d; o.y = v.y / d; o.z = v.z / d; o.w = v.w / d;
  o4[t] = o;
}

// ---------------- A0 = relu(En @ En^T), diag := 1 (symmetric: upper-tri blocks) ----------------
__global__ __launch_bounds__(256) void k_syrk(const float* __restrict__ En,
                                              float* __restrict__ A) {
  int b = blockIdx.x;
  int bi = 0, rem = b;
  while (rem >= (64 - bi)) { rem -= (64 - bi); ++bi; }
  int bj = bi + rem;
  int i0 = bi << 6, j0 = bj << 6;
  __shared__ __align__(16) float Ea[32][68];
  __shared__ __align__(16) float Eb[32][68];
  int t = threadIdx.x;
  int tx = t & 15, ty = t >> 4;
  float acc[4][4] = {};
  for (int k0 = 0; k0 < DD; k0 += 32) {
#pragma unroll
    for (int q = 0; q < 8; q++) {
      int p = (q << 8) + t;
      int r = p >> 5, c = p & 31;
      Ea[c][r] = En[(size_t)(i0 + r) * DD + k0 + c];
      Eb[c][r] = En[(size_t)(j0 + r) * DD + k0 + c];
    }
    __syncthreads();
#pragma unroll
    for (int kk = 0; kk < 32; kk++) {
      float4 av = *(const float4*)&Ea[kk][ty << 2];
      float4 bv = *(const float4*)&Eb[kk][tx << 2];
      float am[4] = {av.x, av.y, av.z, av.w};
      float bn[4] = {bv.x, bv.y, bv.z, bv.w};
#pragma unroll
      for (int m = 0; m < 4; m++)
#pragma unroll
        for (int n = 0; n < 4; n++) acc[m][n] += am[m] * bn[n];
    }
    __syncthreads();
  }
#pragma unroll
  for (int m = 0; m < 4; m++) {
    int gi = i0 + (ty << 2) + m;
#pragma unroll
    for (int n = 0; n < 4; n++) {
      int gj = j0 + (tx << 2) + n;
      float v = fmaxf(acc[m][n], 0.0f);
      if (gi == gj) v = 1.0f;
      A[(size_t)gi * NN + gj] = v;
      if (bi != bj) A[(size_t)gj * NN + gi] = v;
    }
  }
}

// ---------------- sigma[i] = 7th largest of row i (value; exact multiplicity) ----------------
__global__ __launch_bounds__(256) void k_top7(const float* __restrict__ A,
                                              float* __restrict__ sig) {
  int w = threadIdx.x >> 6, lane = threadIdx.x & 63;
  int row = (blockIdx.x << 2) + w;
  const float* a = A + (size_t)row * NN;
  float tv[7];
#pragma unroll
  for (int i = 0; i < 7; i++) tv[i] = -1.0f;
  for (int k = 0; k < NN / 64; k++) {
    float v = a[(k << 6) + lane];
    if (v > tv[6]) {
#pragma unroll
      for (int s = 0; s < 7; s++) {
        if (v > tv[s]) { float tmp = tv[s]; tv[s] = v; v = tmp; }
      }
    }
  }
  // merge 64 sorted lists: pop global max 7 times
  int head = 0;
  float seventh = 0.0f;
  for (int r = 0; r < 7; r++) {
    float h = (head < 7) ? tv[head] : -1.0f;
    float m = h;
#pragma unroll
    for (int off = 32; off; off >>= 1) m = fmaxf(m, __shfl_xor(m, off));
    unsigned long long ball = __ballot(h == m);
    if (lane == (__ffsll(ball) - 1)) head++;
    seventh = m;
  }
  if (lane == 0) sig[row] = seventh;
}

// ---------------- A = exp(-(A^2)/(sig_i*sig_j)); per-row partial sums (double) ----------------
__global__ __launch_bounds__(256) void k_transform(float* __restrict__ A,
                                                   const float* __restrict__ sig,
                                                   double* __restrict__ parts) {
  int row = blockIdx.x;
  float si = sig[row];
  float* a = A + (size_t)row * NN;
  int t = threadIdx.x;
  double local = 0.0;
#pragma unroll
  for (int k = 0; k < NN / 256; k++) {
    int j = (k << 8) + t;
    float v = a[j];
    float w = expf(-(v * v) / (si * sig[j]));
    a[j] = w;
    local += (double)w;
  }
  __shared__ double dred[4];
  int lane = t & 63, wv = t >> 6;
#pragma unroll
  for (int off = 32; off; off >>= 1) local += __shfl_xor(local, off);
  if (lane == 0) dred[wv] = local;
  __syncthreads();
  if (t == 0) parts[row] = dred[0] + dred[1] + dred[2] + dred[3];
}

// ---------------- mean = sum(parts)/N^2 (deterministic) ----------------
__global__ __launch_bounds__(256) void k_mean(const double* __restrict__ parts,
                                              float* __restrict__ meanb) {
  int t = threadIdx.x;
  double local = 0.0;
#pragma unroll
  for (int k = 0; k < NN / 256; k++) local += parts[(k << 8) + t];
  __shared__ double dred[4];
  int lane = t & 63, wv = t >> 6;
#pragma unroll
  for (int off = 32; off; off >>= 1) local += __shfl_xor(local, off);
  if (lane == 0) dred[wv] = local;
  __syncthreads();
  if (t == 0) meanb[0] = (float)((dred[0] + dred[1] + dred[2] + dred[3]) / ((double)NN * (double)NN));
}

// ---------------- threshold: A = (A < mean) ? 0 : A ----------------
__global__ __launch_bounds__(256) void k_thresh(float* __restrict__ A,
                                                const float* __restrict__ meanb) {
  float m = meanb[0];
  size_t i = ((size_t)blockIdx.x << 8) + threadIdx.x;
  float4* a4 = (float4*)A;
  float4 v = a4[i];
  v.x = (v.x < m) ? 0.0f : v.x;
  v.y = (v.y < m) ? 0.0f : v.y;
  v.z = (v.z < m) ? 0.0f : v.z;
  v.w = (v.w < m) ? 0.0f : v.w;
  a4[i] = v;
}

// ---------------- X_lab one-hot [2048][128]; X init 0.01 ----------------
__global__ void k_xlab(const int* __restrict__ labels, float* __restrict__ Xlab) {
  int j = blockIdx.x, t = threadIdx.x;  // 128 threads
  Xlab[(j << 7) + t] = (labels[j] == t) ? 1.0f : 0.0f;
}
__global__ void k_xinit(float* __restrict__ X) {
  int j = blockIdx.x, t = threadIdx.x;
  X[(j << 7) + t] = (t < NC) ? 0.01f : 0.0f;
}

// ---------------- fused GEMM (8 rows x 128 cols per block, K=2048) + optional update ----------------
template <bool UPDATE>
__global__ __launch_bounds__(256) void k_gemm_iter(const float* __restrict__ A,
                                                   int arow0, int acol0,
                                                   const float* __restrict__ Xin,
                                                   const float* __restrict__ Ylab,
                                                   float* __restrict__ Xout) {
  int rb = blockIdx.x;
  int t = threadIdx.x;
  int r = t >> 5, tx = t & 31;
  int row = (rb << 3) + r;  // local unlabeled row 0..2047
  __shared__ __align__(16) float Xs[64][CP];
  __shared__ float As[8][64];
  float4 acc = {0.f, 0.f, 0.f, 0.f};
  for (int k0 = 0; k0 < NLAB; k0 += 64) {
    const float4* xin4 = (const float4*)(Xin + (size_t)k0 * CP);
    float4* xs4 = (float4*)&Xs[0][0];
#pragma unroll
    for (int q = 0; q < 8; q++) xs4[(q << 8) + t] = xin4[(q << 8) + t];
#pragma unroll
    for (int q = 0; q < 2; q++) {
      int p = (q << 8) + t;
      int rr = p >> 6, cc = p & 63;
      As[rr][cc] = A[(size_t)(arow0 + (rb << 3) + rr) * NN + acol0 + k0 + cc];
    }
    __syncthreads();
#pragma unroll
    for (int kk = 0; kk < 64; kk++) {
      float a = As[r][kk];
      float4 x = *(const float4*)&Xs[kk][tx << 2];
      acc.x += a * x.x; acc.y += a * x.y; acc.z += a * x.z; acc.w += a * x.w;
    }
    __syncthreads();
  }
  size_t o = ((size_t)row << 7) + (tx << 2);
  if (!UPDATE) {
    *(float4*)(Xout + o) = acc;
  } else {
    float4 yl = *(const float4*)(Ylab + o);
    float4 x = *(const float4*)(Xin + o);
    float4 mult;
    mult.x = x.x + x.x * (acc.x + yl.x);
    mult.y = x.y + x.y * (acc.y + yl.y);
    mult.z = x.z + x.z * (acc.z + yl.z);
    mult.w = x.w + x.w * (acc.w + yl.w);
    float s = mult.x + mult.y + mult.z + mult.w;
#pragma unroll
    for (int off = 16; off; off >>= 1) s += __shfl_xor(s, off);
    float denom = s + 1e-8f;
    float4 ov;
    ov.x = mult.x / denom; ov.y = mult.y / denom;
    ov.z = mult.z / denom; ov.w = mult.w / denom;
    *(float4*)(Xout + o) = ov;
  }
}

// ---------------- output: labeled rows exact one-hot, unlabeled from X ----------------
__global__ __launch_bounds__(256) void k_output(const float* __restrict__ Xf,
                                                const int* __restrict__ labels,
                                                float* __restrict__ out) {
  int idx = (blockIdx.x << 8) + threadIdx.x;  // 409600 total, exact grid
  int i = idx / NC, c = idx - i * NC;
  float v;
  if (i < NLAB) v = (labels[i] == c) ? 1.0f : 0.0f;
  else v = Xf[((size_t)(i - NLAB) << 7) + c];
  out[idx] = v;
}

extern "C" void kernel_launch(void* const* d_in, const int* in_sizes, int n_in,
                              void* d_out, int out_size, void* d_ws, size_t ws_size,
                              hipStream_t stream) {
  const float* E = (const float*)d_in[0];
  const int* labels = (const int*)d_in[1];
  float* out = (float*)d_out;
  char* w = (char*)d_ws;

  float* A = (float*)w;                               // 64 MB [4096][4096]
  float* En = (float*)(w + (size_t)67108864);         // 16 MB, dead after k_syrk
  // small buffers overlay the (dead) En region after k_syrk:
  float* sig = (float*)(w + (size_t)67108864);        // 16 KB
  double* parts = (double*)(w + (size_t)67108864 + 16384);
  float* meanb = (float*)(w + (size_t)67108864 + 16384 + 32768);
  float* Xlab = (float*)(w + (size_t)67108864 + 16384 + 32768 + 256);
  float* Ylab = Xlab + (size_t)NLAB * CP;
  float* Xa = Ylab + (size_t)NLAB * CP;
  float* Xb = Xa + (size_t)NLAB * CP;

  k_normalize<<<NN, 256, 0, stream>>>(E, En);
  k_syrk<<<2080, 256, 0, stream>>>(En, A);
  k_top7<<<NN / 4, 256, 0, stream>>>(A, sig);
  k_transform<<<NN, 256, 0, stream>>>(A, sig, parts);
  k_mean<<<1, 256, 0, stream>>>(parts, meanb);
  k_thresh<<<16384, 256, 0, stream>>>(A, meanb);
  k_xlab<<<NLAB, 128, 0, stream>>>(labels, Xlab);
  k_xinit<<<NLAB, 128, 0, stream>>>(Xa);
  // Y_lab = A[2048:, :2048] @ onehot  (constant across iterations)
  k_gemm_iter<false><<<256, 256, 0, stream>>>(A, NLAB, 0, Xlab, nullptr, Ylab);
  const float* cur = Xa;
  float* nxt = Xb;
  for (int it = 0; it < NITER; it++) {
    k_gemm_iter<true><<<256, 256, 0, stream>>>(A, NLAB, NLAB, cur, Ylab, nxt);
    float* tmp = (float*)cur;
    cur = nxt;
    nxt = tmp;
  }
  k_output<<<1600, 256, 0, stream>>>(cur, labels, out);
}

// Round 2
// 1331.710 us; speedup vs baseline: 1.3468x; 1.3468x over previous
//
#include <hip/hip_runtime.h>
#include <math.h>

typedef unsigned short ushortT;
typedef __attribute__((ext_vector_type(8))) short short8;
typedef __attribute__((ext_vector_type(4))) float f32x4;

#define NN 4096
#define DD 1024
#define NC 100
#define CP 128
#define NLAB 2048
#define NITER 30

__device__ __forceinline__ ushortT bf16rn(float x) {
  unsigned u = __float_as_uint(x);
  unsigned r = (u + 0x7fffu + ((u >> 16) & 1u)) >> 16;
  return (ushortT)r;
}
__device__ __forceinline__ float bf2f(ushortT h) {
  return __uint_as_float(((unsigned)h) << 16);
}
__device__ __forceinline__ void gload16(const void* g, void* l) {
  __builtin_amdgcn_global_load_lds((const __attribute__((address_space(1))) char*)g,
                                   (__attribute__((address_space(3))) char*)l, 16, 0, 0);
}

// ---------------- normalize rows -> bf16 hi/lo splits ----------------
__global__ __launch_bounds__(256) void k_normalize(const float* __restrict__ E,
                                                   ushortT* __restrict__ Enh,
                                                   ushortT* __restrict__ Enl) {
  int row = blockIdx.x, t = threadIdx.x;
  const float4* e4 = (const float4*)(E + (size_t)row * DD);
  float4 v = e4[t];
  float ss = v.x * v.x + v.y * v.y + v.z * v.z + v.w * v.w;
  __shared__ float red[4];
  int lane = t & 63, w = t >> 6;
#pragma unroll
  for (int off = 32; off; off >>= 1) ss += __shfl_xor(ss, off);
  if (lane == 0) red[w] = ss;
  __syncthreads();
  float tot = red[0] + red[1] + red[2] + red[3];
  float d = fmaxf(sqrtf(tot), 1e-12f);
  float xs[4] = {v.x / d, v.y / d, v.z / d, v.w / d};
  ushort4 hv, lv;
  ushortT h;
  h = bf16rn(xs[0]); hv.x = h; lv.x = bf16rn(xs[0] - bf2f(h));
  h = bf16rn(xs[1]); hv.y = h; lv.y = bf16rn(xs[1] - bf2f(h));
  h = bf16rn(xs[2]); hv.z = h; lv.z = bf16rn(xs[2] - bf2f(h));
  h = bf16rn(xs[3]); hv.w = h; lv.w = bf16rn(xs[3] - bf2f(h));
  ((ushort4*)Enh)[(size_t)row * 256 + t] = hv;
  ((ushort4*)Enl)[(size_t)row * 256 + t] = lv;
}

// ---------------- A0 = relu(En@En^T) via MFMA, 3-term bf16 split; diag=1 ----------------
__global__ __launch_bounds__(256) void k_syrk_mfma(const ushortT* __restrict__ Enh,
                                                   const ushortT* __restrict__ Enl,
                                                   float* __restrict__ A) {
  __shared__ ushortT lds[16384];  // A-tile [128][64] @0, B-tile @8192
  int t = threadIdx.x;
  int l = t & 63, w = t >> 6;
  int bi = blockIdx.x >> 5, bj = blockIdx.x & 31;
  int i0 = bi << 7, j0 = bj << 7;
  int wr = w >> 1, wc = w & 1;
  f32x4 zz = {0.f, 0.f, 0.f, 0.f};
  f32x4 acc[4][4];
#pragma unroll
  for (int m = 0; m < 4; ++m)
#pragma unroll
    for (int n = 0; n < 4; ++n) acc[m][n] = zz;
  int arow_l = l & 15, kslot = l >> 4;
  for (int s = 0; s < 48; ++s) {
    int term = s >> 4;
    int kk0 = (s & 15) << 6;
    const ushortT* sa = (term == 2) ? Enl : Enh;
    const ushortT* sb = (term == 1) ? Enl : Enh;
#pragma unroll
    for (int q = 0; q < 4; ++q) {
      int n = (q << 8) + t;
      int r = n >> 3, p = n & 7;
      int col = (p ^ (r & 7)) << 3;
      gload16(sa + (size_t)(i0 + r) * DD + kk0 + col, &lds[n << 3]);
      gload16(sb + (size_t)(j0 + r) * DD + kk0 + col, &lds[8192 + (n << 3)]);
    }
    __syncthreads();
#pragma unroll
    for (int kk = 0; kk < 2; ++kk) {
      int g = (kk << 2) + kslot;
      short8 av[4], bv[4];
#pragma unroll
      for (int m = 0; m < 4; ++m) {
        int r = (wr << 6) + (m << 4) + arow_l;
        av[m] = *(const short8*)&lds[(r << 6) + ((g ^ (r & 7)) << 3)];
      }
#pragma unroll
      for (int n = 0; n < 4; ++n) {
        int r = (wc << 6) + (n << 4) + arow_l;
        bv[n] = *(const short8*)&lds[8192 + (r << 6) + ((g ^ (r & 7)) << 3)];
      }
#pragma unroll
      for (int m = 0; m < 4; ++m)
#pragma unroll
        for (int n = 0; n < 4; ++n)
          acc[m][n] = __builtin_amdgcn_mfma_f32_16x16x32_bf16(av[m], bv[n], acc[m][n], 0, 0, 0);
    }
    __syncthreads();
  }
  int rbase = (l >> 4) << 2;
#pragma unroll
  for (int m = 0; m < 4; ++m) {
#pragma unroll
    for (int n = 0; n < 4; ++n) {
#pragma unroll
      for (int r = 0; r < 4; ++r) {
        int gi = i0 + (wr << 6) + (m << 4) + rbase + r;
        int gj = j0 + (wc << 6) + (n << 4) + (l & 15);
        float v = fmaxf(acc[m][n][r], 0.0f);
        if (gi == gj) v = 1.0f;
        A[(size_t)gi * NN + gj] = v;
      }
    }
  }
}

// ---------------- sigma[i] = 7th largest of row i ----------------
__global__ __launch_bounds__(256) void k_top7(const float* __restrict__ A,
                                              float* __restrict__ sig) {
  int w = threadIdx.x >> 6, lane = threadIdx.x & 63;
  int row = (blockIdx.x << 2) + w;
  const float* a = A + (size_t)row * NN;
  float tv[7];
#pragma unroll
  for (int i = 0; i < 7; i++) tv[i] = -1.0f;
  for (int k = 0; k < NN / 64; k++) {
    float v = a[(k << 6) + lane];
    if (v > tv[6]) {
#pragma unroll
      for (int s = 0; s < 7; s++) {
        if (v > tv[s]) { float tmp = tv[s]; tv[s] = v; v = tmp; }
      }
    }
  }
  int head = 0;
  float seventh = 0.0f;
  for (int r = 0; r < 7; r++) {
    float h = (head < 7) ? tv[head] : -1.0f;
    float m = h;
#pragma unroll
    for (int off = 32; off; off >>= 1) m = fmaxf(m, __shfl_xor(m, off));
    unsigned long long ball = __ballot(h == m);
    if (lane == (__ffsll(ball) - 1)) head++;
    seventh = m;
  }
  if (lane == 0) sig[row] = seventh;
}

// ---------------- transform all rows for mean; store only bottom half ----------------
__global__ __launch_bounds__(256) void k_transform(float* __restrict__ A,
                                                   const float* __restrict__ sig,
                                                   double* __restrict__ parts) {
  int row = blockIdx.x;
  float si = sig[row];
  float* a = A + (size_t)row * NN;
  int t = threadIdx.x;
  bool store = (row >= NLAB);
  double local = 0.0;
#pragma unroll
  for (int k = 0; k < NN / 256; k++) {
    int j = (k << 8) + t;
    float v = a[j];
    float w = expf(-(v * v) / (si * sig[j]));
    if (store) a[j] = w;
    local += (double)w;
  }
  __shared__ double dred[4];
  int lane = t & 63, wv = t >> 6;
#pragma unroll
  for (int off = 32; off; off >>= 1) local += __shfl_xor(local, off);
  if (lane == 0) dred[wv] = local;
  __syncthreads();
  if (t == 0) parts[row] = dred[0] + dred[1] + dred[2] + dred[3];
}

__global__ __launch_bounds__(256) void k_mean(const double* __restrict__ parts,
                                              float* __restrict__ meanb) {
  int t = threadIdx.x;
  double local = 0.0;
#pragma unroll
  for (int k = 0; k < NN / 256; k++) local += parts[(k << 8) + t];
  __shared__ double dred[4];
  int lane = t & 63, wv = t >> 6;
#pragma unroll
  for (int off = 32; off; off >>= 1) local += __shfl_xor(local, off);
  if (lane == 0) dred[wv] = local;
  __syncthreads();
  if (t == 0) meanb[0] = (float)((dred[0] + dred[1] + dred[2] + dred[3]) / ((double)NN * (double)NN));
}

// ---------------- threshold bottom half + bf16 hi/lo split ----------------
__global__ __launch_bounds__(256) void k_thresh_bf(const float* __restrict__ A,
                                                   const float* __restrict__ meanb,
                                                   ushortT* __restrict__ Abh,
                                                   ushortT* __restrict__ Abl) {
  float m = meanb[0];
  size_t i4 = ((size_t)blockIdx.x << 8) + threadIdx.x;  // over 2048*4096/4
  float4 v = ((const float4*)(A + (size_t)NLAB * NN))[i4];
  float c0 = (v.x < m) ? 0.0f : v.x;
  float c1 = (v.y < m) ? 0.0f : v.y;
  float c2 = (v.z < m) ? 0.0f : v.z;
  float c3 = (v.w < m) ? 0.0f : v.w;
  ushort4 hv, lv;
  ushortT h;
  h = bf16rn(c0); hv.x = h; lv.x = bf16rn(c0 - bf2f(h));
  h = bf16rn(c1); hv.y = h; lv.y = bf16rn(c1 - bf2f(h));
  h = bf16rn(c2); hv.z = h; lv.z = bf16rn(c2 - bf2f(h));
  h = bf16rn(c3); hv.w = h; lv.w = bf16rn(c3 - bf2f(h));
  ((ushort4*)Abh)[i4] = hv;
  ((ushort4*)Abl)[i4] = lv;
}

// ---------------- one-hot labels, transposed bf16 [128][2048] ----------------
__global__ __launch_bounds__(256) void k_xlabt(const int* __restrict__ labels,
                                               ushortT* __restrict__ Xlabt) {
  int idx = (blockIdx.x << 8) + threadIdx.x;  // 262144
  int c = idx >> 11, j = idx & 2047;
  Xlabt[idx] = (labels[j] == c) ? (ushortT)0x3F80 : (ushortT)0;
}

// ---------------- X init: fp32 [2048][128] + transposed bf16 splits ----------------
__global__ __launch_bounds__(256) void k_xinit(float* __restrict__ Xf,
                                               ushortT* __restrict__ Xth,
                                               ushortT* __restrict__ Xtl) {
  int idx = (blockIdx.x << 8) + threadIdx.x;  // 262144 over [2048][128]
  int i = idx >> 7, c = idx & 127;
  float v = (c < NC) ? 0.01f : 0.0f;
  Xf[idx] = v;
  ushortT h = bf16rn(v);
  Xth[(size_t)c * NLAB + i] = h;
  Xtl[(size_t)c * NLAB + i] = bf16rn(v - bf2f(h));
}

// ---------------- MFMA iteration: mm = A(rows)@X (3-term bf16 split), fused update ----------------
template <bool UPDATE, int NT>
__global__ __launch_bounds__(256) void k_iter(
    const ushortT* __restrict__ Abh, const ushortT* __restrict__ Abl, int acol0,
    const ushortT* __restrict__ Xh, const ushortT* __restrict__ Xl,
    const float* __restrict__ Ylab, const float* __restrict__ Xprev,
    float* __restrict__ outF, ushortT* __restrict__ outTh, ushortT* __restrict__ outTl) {
  __shared__ ushortT lds[2][18432];  // per buf: A-tile [16][128] @0, X-tile [128][128] @2048
  int t = threadIdx.x, l = t & 63, w = t >> 6;
  int brow0 = blockIdx.x << 4;
  f32x4 zz = {0.f, 0.f, 0.f, 0.f};
  f32x4 acc[2];
  acc[0] = zz; acc[1] = zz;

  auto stage = [&](int b, int s) {
    int term = s >> 4;
    int kk0 = (s & 15) << 7;
    const ushortT* sa = (term == 1) ? Abl : Abh;
    const ushortT* sx = (term == 2) ? Xl : Xh;
    {
      int r = t >> 4, p = t & 15;
      gload16(sa + (size_t)(brow0 + r) * NN + acol0 + kk0 + ((p ^ (r & 7)) << 3),
              &lds[b][t << 3]);
    }
#pragma unroll
    for (int q = 0; q < 8; ++q) {
      int n = (q << 8) + t;
      int r = n >> 4, p = n & 15;
      gload16(sx + (size_t)r * NLAB + kk0 + ((p ^ (r & 7)) << 3),
              &lds[b][2048 + (n << 3)]);
    }
  };

  stage(0, 0);
  __syncthreads();
  int cur = 0;
  const int NSTEPS = NT << 4;
  int arow = l & 15, kslot = l >> 4;
  for (int s = 0; s < NSTEPS; ++s) {
    if (s + 1 < NSTEPS) stage(cur ^ 1, s + 1);
#pragma unroll
    for (int kk = 0; kk < 4; ++kk) {
      int g = (kk << 2) + kslot;
      short8 av = *(const short8*)&lds[cur][(arow << 7) + ((g ^ (arow & 7)) << 3)];
#pragma unroll
      for (int n = 0; n < 2; ++n) {
        int c = (w << 5) + (n << 4) + arow;
        short8 bv = *(const short8*)&lds[cur][2048 + (c << 7) + ((g ^ (c & 7)) << 3)];
        acc[n] = __builtin_amdgcn_mfma_f32_16x16x32_bf16(av, bv, acc[n], 0, 0, 0);
      }
    }
    __syncthreads();
    cur ^= 1;
  }

  int rbase = (l >> 4) << 2;
  if constexpr (!UPDATE) {
#pragma unroll
    for (int n = 0; n < 2; ++n)
#pragma unroll
      for (int r = 0; r < 4; ++r) {
        int gi = brow0 + rbase + r;
        int c = (w << 5) + (n << 4) + (l & 15);
        outF[(size_t)gi * CP + c] = acc[n][r];
      }
  } else {
    float* red = (float*)&lds[0][0];
    float mult[2][4], sreg[4];
#pragma unroll
    for (int r = 0; r < 4; ++r) {
      int gi = brow0 + rbase + r;
      float s = 0.f;
#pragma unroll
      for (int n = 0; n < 2; ++n) {
        int c = (w << 5) + (n << 4) + (l & 15);
        float mmv = acc[n][r] + Ylab[(size_t)gi * CP + c];
        float x = Xprev[(size_t)gi * CP + c];
        float mv = x + x * mmv;
        mult[n][r] = mv;
        s += mv;
      }
#pragma unroll
      for (int off = 8; off; off >>= 1) s += __shfl_xor(s, off);
      sreg[r] = s;
    }
    if ((l & 15) == 0) {
#pragma unroll
      for (int r = 0; r < 4; ++r) red[(w << 4) + rbase + r] = sreg[r];
    }
    __syncthreads();
    float tot[4];
#pragma unroll
    for (int r = 0; r < 4; ++r) {
      int il = rbase + r;
      tot[r] = red[il] + red[16 + il] + red[32 + il] + red[48 + il] + 1e-8f;
    }
#pragma unroll
    for (int n = 0; n < 2; ++n) {
      int c = (w << 5) + (n << 4) + (l & 15);
      float ov[4];
      ushort4 hp, lp;
#pragma unroll
      for (int r = 0; r < 4; ++r) {
        ov[r] = mult[n][r] / tot[r];
        outF[(size_t)(brow0 + rbase + r) * CP + c] = ov[r];
      }
      ushortT h;
      h = bf16rn(ov[0]); hp.x = h; lp.x = bf16rn(ov[0] - bf2f(h));
      h = bf16rn(ov[1]); hp.y = h; lp.y = bf16rn(ov[1] - bf2f(h));
      h = bf16rn(ov[2]); hp.z = h; lp.z = bf16rn(ov[2] - bf2f(h));
      h = bf16rn(ov[3]); hp.w = h; lp.w = bf16rn(ov[3] - bf2f(h));
      size_t to = (size_t)c * NLAB + brow0 + rbase;
      *(ushort4*)&outTh[to] = hp;
      *(ushort4*)&outTl[to] = lp;
    }
  }
}

// ---------------- output assembly ----------------
__global__ __launch_bounds__(256) void k_output(const float* __restrict__ Xf,
                                                const int* __restrict__ labels,
                                                float* __restrict__ out) {
  int idx = (blockIdx.x << 8) + threadIdx.x;  // 409600
  int i = idx / NC, c = idx - i * NC;
  float v;
  if (i < NLAB) v = (labels[i] == c) ? 1.0f : 0.0f;
  else v = Xf[((size_t)(i - NLAB) << 7) + c];
  out[idx] = v;
}

extern "C" void kernel_launch(void* const* d_in, const int* in_sizes, int n_in,
                              void* d_out, int out_size, void* d_ws, size_t ws_size,
                              hipStream_t stream) {
  const float* E = (const float*)d_in[0];
  const int* labels = (const int*)d_in[1];
  float* out = (float*)d_out;
  char* ws = (char*)d_ws;
  const size_t MB = 1024 * 1024;

  float* A = (float*)ws;                          // 64 MB
  ushortT* Enh = (ushortT*)(ws + 64 * MB);        // 8 MB
  ushortT* Enl = (ushortT*)(ws + 72 * MB);        // 8 MB
  ushortT* Abh = (ushortT*)(ws + 80 * MB);        // 16 MB [2048][4096] bf16
  ushortT* Abl = (ushortT*)(ws + 96 * MB);        // 16 MB
  float* sig = (float*)(ws + 112 * MB);
  double* parts = (double*)(ws + 112 * MB + 65536);
  float* meanb = (float*)(ws + 112 * MB + 131072);
  ushortT* Xlabt = (ushortT*)(ws + 113 * MB);     // 0.5 MB [128][2048]
  float* Ylab = (float*)(ws + 114 * MB);          // 1 MB
  float* Xf0 = (float*)(ws + 115 * MB);
  float* Xf1 = (float*)(ws + 116 * MB);
  ushortT* Xth0 = (ushortT*)(ws + 117 * MB);
  ushortT* Xtl0 = (ushortT*)(ws + 117 * MB + 524288);
  ushortT* Xth1 = (ushortT*)(ws + 118 * MB);
  ushortT* Xtl1 = (ushortT*)(ws + 118 * MB + 524288);

  k_normalize<<<NN, 256, 0, stream>>>(E, Enh, Enl);
  k_syrk_mfma<<<1024, 256, 0, stream>>>(Enh, Enl, A);
  k_top7<<<NN / 4, 256, 0, stream>>>(A, sig);
  k_transform<<<NN, 256, 0, stream>>>(A, sig, parts);
  k_mean<<<1, 256, 0, stream>>>(parts, meanb);
  k_thresh_bf<<<8192, 256, 0, stream>>>(A, meanb, Abh, Abl);
  k_xlabt<<<1024, 256, 0, stream>>>(labels, Xlabt);
  k_xinit<<<1024, 256, 0, stream>>>(Xf0, Xth0, Xtl0);
  // Ylab = (Ah+Al)[unlab, :2048] @ onehot
  k_iter<false, 2><<<128, 256, 0, stream>>>(Abh, Abl, 0, Xlabt, Xlabt,
                                            nullptr, nullptr, Ylab, nullptr, nullptr);
  float* xf[2] = {Xf0, Xf1};
  ushortT* xh[2] = {Xth0, Xth1};
  ushortT* xl[2] = {Xtl0, Xtl1};
  int cur = 0;
  for (int it = 0; it < NITER; ++it) {
    int nxt = cur ^ 1;
    k_iter<true, 3><<<128, 256, 0, stream>>>(Abh, Abl, NLAB, xh[cur], xl[cur],
                                             Ylab, xf[cur], xf[nxt], xh[nxt], xl[nxt]);
    cur = nxt;
  }
  k_output<<<1600, 256, 0, stream>>>(xf[cur], labels, out);
}

// Round 3
// 954.334 us; speedup vs baseline: 1.8793x; 1.3954x over previous
//
#include <hip/hip_runtime.h>
#include <math.h>

typedef unsigned short ushortT;
typedef __attribute__((ext_vector_type(8))) short short8;
typedef __attribute__((ext_vector_type(4))) float f32x4;

#define NN 4096
#define DD 1024
#define NC 100
#define CP 128
#define NLAB 2048
#define NITER 30

__device__ __forceinline__ ushortT bf16rn(float x) {
  unsigned u = __float_as_uint(x);
  unsigned r = (u + 0x7fffu + ((u >> 16) & 1u)) >> 16;
  return (ushortT)r;
}
__device__ __forceinline__ float bf2f(ushortT h) {
  return __uint_as_float(((unsigned)h) << 16);
}
__device__ __forceinline__ void gload16(const void* g, void* l) {
  __builtin_amdgcn_global_load_lds((const __attribute__((address_space(1))) char*)g,
                                   (__attribute__((address_space(3))) char*)l, 16, 0, 0);
}

// ---------------- normalize rows -> bf16 hi/lo splits ----------------
__global__ __launch_bounds__(256) void k_normalize(const float* __restrict__ E,
                                                   ushortT* __restrict__ Enh,
                                                   ushortT* __restrict__ Enl) {
  int row = blockIdx.x, t = threadIdx.x;
  const float4* e4 = (const float4*)(E + (size_t)row * DD);
  float4 v = e4[t];
  float ss = v.x * v.x + v.y * v.y + v.z * v.z + v.w * v.w;
  __shared__ float red[4];
  int lane = t & 63, w = t >> 6;
#pragma unroll
  for (int off = 32; off; off >>= 1) ss += __shfl_xor(ss, off);
  if (lane == 0) red[w] = ss;
  __syncthreads();
  float tot = red[0] + red[1] + red[2] + red[3];
  float d = fmaxf(sqrtf(tot), 1e-12f);
  float xs[4] = {v.x / d, v.y / d, v.z / d, v.w / d};
  ushort4 hv, lv;
  ushortT h;
  h = bf16rn(xs[0]); hv.x = h; lv.x = bf16rn(xs[0] - bf2f(h));
  h = bf16rn(xs[1]); hv.y = h; lv.y = bf16rn(xs[1] - bf2f(h));
  h = bf16rn(xs[2]); hv.z = h; lv.z = bf16rn(xs[2] - bf2f(h));
  h = bf16rn(xs[3]); hv.w = h; lv.w = bf16rn(xs[3] - bf2f(h));
  ((ushort4*)Enh)[(size_t)row * 256 + t] = hv;
  ((ushort4*)Enl)[(size_t)row * 256 + t] = lv;
}

// ---------------- A0 = relu(En@En^T) via MFMA, 3-term bf16 split; diag=1 ----------------
// 2-buf LDS, stage-ahead + counted vmcnt + raw barriers (T3-minimum), XCD swizzle.
__global__ __launch_bounds__(256) void k_syrk_mfma(const ushortT* __restrict__ Enh,
                                                   const ushortT* __restrict__ Enl,
                                                   float* __restrict__ A) {
  __shared__ ushortT lds[2][16384];  // per buf: A-tile [128][64] @0, B-tile @8192
  int t = threadIdx.x;
  int l = t & 63, w = t >> 6;
  int bid = blockIdx.x;
  int swz = ((bid & 7) << 7) + (bid >> 3);  // 1024 blocks, 8 XCDs, bijective
  int bi = swz >> 5, bj = swz & 31;
  int i0 = bi << 7, j0 = bj << 7;
  int wr = w >> 1, wc = w & 1;
  f32x4 zz = {0.f, 0.f, 0.f, 0.f};
  f32x4 acc[4][4];
#pragma unroll
  for (int m = 0; m < 4; ++m)
#pragma unroll
    for (int n = 0; n < 4; ++n) acc[m][n] = zz;
  int arow_l = l & 15, kslot = l >> 4;

  auto stage = [&](int b, int s) {
    int term = s >> 4;
    int kk0 = (s & 15) << 6;
    const ushortT* sa = (term == 2) ? Enl : Enh;
    const ushortT* sb = (term == 1) ? Enl : Enh;
#pragma unroll
    for (int q = 0; q < 4; ++q) {
      int n = (q << 8) + t;
      int r = n >> 3, p = n & 7;
      int col = (p ^ (r & 7)) << 3;
      gload16(sa + (size_t)(i0 + r) * DD + kk0 + col, &lds[b][n << 3]);
      gload16(sb + (size_t)(j0 + r) * DD + kk0 + col, &lds[b][8192 + (n << 3)]);
    }
  };

  stage(0, 0);
  int cur = 0;
  for (int s = 0; s < 48; ++s) {
    if (s < 47) {
      stage(cur ^ 1, s + 1);
      asm volatile("s_waitcnt vmcnt(8)" ::: "memory");
    } else {
      asm volatile("s_waitcnt vmcnt(0)" ::: "memory");
    }
    __builtin_amdgcn_s_barrier();
#pragma unroll
    for (int kk = 0; kk < 2; ++kk) {
      int g = (kk << 2) + kslot;
      short8 av[4], bv[4];
#pragma unroll
      for (int m = 0; m < 4; ++m) {
        int r = (wr << 6) + (m << 4) + arow_l;
        av[m] = *(const short8*)&lds[cur][(r << 6) + ((g ^ (r & 7)) << 3)];
      }
#pragma unroll
      for (int n = 0; n < 4; ++n) {
        int r = (wc << 6) + (n << 4) + arow_l;
        bv[n] = *(const short8*)&lds[cur][8192 + (r << 6) + ((g ^ (r & 7)) << 3)];
      }
#pragma unroll
      for (int m = 0; m < 4; ++m)
#pragma unroll
        for (int n = 0; n < 4; ++n)
          acc[m][n] = __builtin_amdgcn_mfma_f32_16x16x32_bf16(av[m], bv[n], acc[m][n], 0, 0, 0);
    }
    asm volatile("s_waitcnt lgkmcnt(0)" ::: "memory");
    __builtin_amdgcn_s_barrier();
    cur ^= 1;
  }
  int rbase = (l >> 4) << 2;
#pragma unroll
  for (int m = 0; m < 4; ++m) {
#pragma unroll
    for (int n = 0; n < 4; ++n) {
#pragma unroll
      for (int r = 0; r < 4; ++r) {
        int gi = i0 + (wr << 6) + (m << 4) + rbase + r;
        int gj = j0 + (wc << 6) + (n << 4) + (l & 15);
        float v = fmaxf(acc[m][n][r], 0.0f);
        if (gi == gj) v = 1.0f;
        A[(size_t)gi * NN + gj] = v;
      }
    }
  }
}

// ---------------- sigma[i] = 7th largest of row i ----------------
__global__ __launch_bounds__(256) void k_top7(const float* __restrict__ A,
                                              float* __restrict__ sig) {
  int w = threadIdx.x >> 6, lane = threadIdx.x & 63;
  int row = (blockIdx.x << 2) + w;
  const float* a = A + (size_t)row * NN;
  float tv[7];
#pragma unroll
  for (int i = 0; i < 7; i++) tv[i] = -1.0f;
  for (int k = 0; k < NN / 64; k++) {
    float v = a[(k << 6) + lane];
    if (v > tv[6]) {
#pragma unroll
      for (int s = 0; s < 7; s++) {
        if (v > tv[s]) { float tmp = tv[s]; tv[s] = v; v = tmp; }
      }
    }
  }
  int head = 0;
  float seventh = 0.0f;
  for (int r = 0; r < 7; r++) {
    float h = (head < 7) ? tv[head] : -1.0f;
    float m = h;
#pragma unroll
    for (int off = 32; off; off >>= 1) m = fmaxf(m, __shfl_xor(m, off));
    unsigned long long ball = __ballot(h == m);
    if (lane == (__ffsll(ball) - 1)) head++;
    seventh = m;
  }
  if (lane == 0) sig[row] = seventh;
}

// ---------------- transform all rows for mean; store only bottom half ----------------
__global__ __launch_bounds__(256) void k_transform(float* __restrict__ A,
                                                   const float* __restrict__ sig,
                                                   double* __restrict__ parts) {
  int row = blockIdx.x;
  float si = sig[row];
  float* a = A + (size_t)row * NN;
  int t = threadIdx.x;
  bool store = (row >= NLAB);
  double local = 0.0;
#pragma unroll
  for (int k = 0; k < NN / 256; k++) {
    int j = (k << 8) + t;
    float v = a[j];
    float w = expf(-(v * v) / (si * sig[j]));
    if (store) a[j] = w;
    local += (double)w;
  }
  __shared__ double dred[4];
  int lane = t & 63, wv = t >> 6;
#pragma unroll
  for (int off = 32; off; off >>= 1) local += __shfl_xor(local, off);
  if (lane == 0) dred[wv] = local;
  __syncthreads();
  if (t == 0) parts[row] = dred[0] + dred[1] + dred[2] + dred[3];
}

__global__ __launch_bounds__(256) void k_mean(const double* __restrict__ parts,
                                              float* __restrict__ meanb) {
  int t = threadIdx.x;
  double local = 0.0;
#pragma unroll
  for (int k = 0; k < NN / 256; k++) local += parts[(k << 8) + t];
  __shared__ double dred[4];
  int lane = t & 63, wv = t >> 6;
#pragma unroll
  for (int off = 32; off; off >>= 1) local += __shfl_xor(local, off);
  if (lane == 0) dred[wv] = local;
  __syncthreads();
  if (t == 0) meanb[0] = (float)((dred[0] + dred[1] + dred[2] + dred[3]) / ((double)NN * (double)NN));
}

// ---------------- threshold bottom half + bf16 hi/lo split ----------------
__global__ __launch_bounds__(256) void k_thresh_bf(const float* __restrict__ A,
                                                   const float* __restrict__ meanb,
                                                   ushortT* __restrict__ Abh,
                                                   ushortT* __restrict__ Abl) {
  float m = meanb[0];
  size_t i4 = ((size_t)blockIdx.x << 8) + threadIdx.x;  // over 2048*4096/4
  float4 v = ((const float4*)(A + (size_t)NLAB * NN))[i4];
  float c0 = (v.x < m) ? 0.0f : v.x;
  float c1 = (v.y < m) ? 0.0f : v.y;
  float c2 = (v.z < m) ? 0.0f : v.z;
  float c3 = (v.w < m) ? 0.0f : v.w;
  ushort4 hv, lv;
  ushortT h;
  h = bf16rn(c0); hv.x = h; lv.x = bf16rn(c0 - bf2f(h));
  h = bf16rn(c1); hv.y = h; lv.y = bf16rn(c1 - bf2f(h));
  h = bf16rn(c2); hv.z = h; lv.z = bf16rn(c2 - bf2f(h));
  h = bf16rn(c3); hv.w = h; lv.w = bf16rn(c3 - bf2f(h));
  ((ushort4*)Abh)[i4] = hv;
  ((ushort4*)Abl)[i4] = lv;
}

// ---------------- one-hot labels, transposed bf16 [128][2048] ----------------
__global__ __launch_bounds__(256) void k_xlabt(const int* __restrict__ labels,
                                               ushortT* __restrict__ Xlabt) {
  int idx = (blockIdx.x << 8) + threadIdx.x;  // 262144
  int c = idx >> 11, j = idx & 2047;
  Xlabt[idx] = (labels[j] == c) ? (ushortT)0x3F80 : (ushortT)0;
}

// ---------------- X init: fp32 [2048][128] + transposed bf16 ----------------
__global__ __launch_bounds__(256) void k_xinit(float* __restrict__ Xf,
                                               ushortT* __restrict__ Xth) {
  int idx = (blockIdx.x << 8) + threadIdx.x;  // 262144 over [2048][128]
  int i = idx >> 7, c = idx & 127;
  float v = (c < NC) ? 0.01f : 0.0f;
  Xf[idx] = v;
  Xth[(size_t)c * NLAB + i] = bf16rn(v);
}

// ---------------- iteration: mm = A@X (2-term: Ah@Xh + Al@Xh), no-LDS main loop ----------------
// 8 waves K-split (256 each); frags global->reg; one LDS K-reduce + fused update.
template <bool UPDATE>
__global__ __launch_bounds__(512) void k_iter(
    const ushortT* __restrict__ Ah, const ushortT* __restrict__ Al, int acol0,
    const ushortT* __restrict__ Xt,  // [128][2048] bf16 (class-major / transposed)
    const float* __restrict__ Ylab, const float* __restrict__ Xprev,
    float* __restrict__ outF, ushortT* __restrict__ outTh) {
  __shared__ float red[8 * 128 * 20];  // [wave][col(128)][row(16)] stride-20: 80 KB
  int t = threadIdx.x, l = t & 63, w = t >> 6;
  int brow0 = blockIdx.x << 4;
  int arow = l & 15, khi = l >> 4;
  int kb = w << 8;  // wave's K-slice base (256 wide)
  f32x4 acc[8];
#pragma unroll
  for (int ct = 0; ct < 8; ++ct) acc[ct] = (f32x4){0.f, 0.f, 0.f, 0.f};

  const ushortT* aph = Ah + (size_t)(brow0 + arow) * NN + acol0 + kb + (khi << 3);
  const ushortT* apl = Al + (size_t)(brow0 + arow) * NN + acol0 + kb + (khi << 3);
  const ushortT* xp = Xt + (size_t)arow * NLAB + kb + (khi << 3);
#pragma unroll
  for (int g = 0; g < 8; ++g) {
    short8 ahv = *(const short8*)(aph + (g << 5));
    short8 alv = *(const short8*)(apl + (g << 5));
#pragma unroll
    for (int ct = 0; ct < 8; ++ct) {
      short8 bv = *(const short8*)(xp + ((size_t)ct << 15) + (g << 5));
      acc[ct] = __builtin_amdgcn_mfma_f32_16x16x32_bf16(ahv, bv, acc[ct], 0, 0, 0);
      acc[ct] = __builtin_amdgcn_mfma_f32_16x16x32_bf16(alv, bv, acc[ct], 0, 0, 0);
    }
  }
  // write per-wave partials: value for (row=khi*4+r, col=ct*16+arow)
  int rbase = khi << 2;
#pragma unroll
  for (int ct = 0; ct < 8; ++ct)
    *(f32x4*)&red[(w << 11) + (w << 8) + ((ct << 4) + arow) * 20 + rbase] = acc[ct];
  __syncthreads();

  // K-reduce: thread -> (row = t>>5, cols c4..c4+3)
  int row = t >> 5;
  int c4 = (t & 31) << 2;
  int gi = brow0 + row;
  float mm[4];
#pragma unroll
  for (int j = 0; j < 4; ++j) {
    float s = 0.f;
#pragma unroll
    for (int w2 = 0; w2 < 8; ++w2)
      s += red[(w2 << 11) + (w2 << 8) + (c4 + j) * 20 + row];
    mm[j] = s;
  }
  if constexpr (!UPDATE) {
    float4 o = {mm[0], mm[1], mm[2], mm[3]};
    *(float4*)&outF[(size_t)gi * CP + c4] = o;
  } else {
    float4 yl = *(const float4*)&Ylab[(size_t)gi * CP + c4];
    float4 xv = *(const float4*)&Xprev[(size_t)gi * CP + c4];
    float mult[4];
    mult[0] = fmaf(xv.x, mm[0] + yl.x, xv.x);
    mult[1] = fmaf(xv.y, mm[1] + yl.y, xv.y);
    mult[2] = fmaf(xv.z, mm[2] + yl.z, xv.z);
    mult[3] = fmaf(xv.w, mm[3] + yl.w, xv.w);
    float s = mult[0] + mult[1] + mult[2] + mult[3];
#pragma unroll
    for (int off = 16; off; off >>= 1) s += __shfl_xor(s, off);
    float denom = s + 1e-8f;
    float4 o;
    o.x = mult[0] / denom; o.y = mult[1] / denom;
    o.z = mult[2] / denom; o.w = mult[3] / denom;
    *(float4*)&outF[(size_t)gi * CP + c4] = o;
    outTh[(size_t)(c4 + 0) * NLAB + gi] = bf16rn(o.x);
    outTh[(size_t)(c4 + 1) * NLAB + gi] = bf16rn(o.y);
    outTh[(size_t)(c4 + 2) * NLAB + gi] = bf16rn(o.z);
    outTh[(size_t)(c4 + 3) * NLAB + gi] = bf16rn(o.w);
  }
}

// ---------------- output assembly ----------------
__global__ __launch_bounds__(256) void k_output(const float* __restrict__ Xf,
                                                const int* __restrict__ labels,
                                                float* __restrict__ out) {
  int idx = (blockIdx.x << 8) + threadIdx.x;  // 409600
  int i = idx / NC, c = idx - i * NC;
  float v;
  if (i < NLAB) v = (labels[i] == c) ? 1.0f : 0.0f;
  else v = Xf[((size_t)(i - NLAB) << 7) + c];
  out[idx] = v;
}

extern "C" void kernel_launch(void* const* d_in, const int* in_sizes, int n_in,
                              void* d_out, int out_size, void* d_ws, size_t ws_size,
                              hipStream_t stream) {
  const float* E = (const float*)d_in[0];
  const int* labels = (const int*)d_in[1];
  float* out = (float*)d_out;
  char* ws = (char*)d_ws;
  const size_t MB = 1024 * 1024;

  float* A = (float*)ws;                          // 64 MB
  ushortT* Enh = (ushortT*)(ws + 64 * MB);        // 8 MB
  ushortT* Enl = (ushortT*)(ws + 72 * MB);        // 8 MB
  ushortT* Abh = (ushortT*)(ws + 80 * MB);        // 16 MB [2048][4096] bf16
  ushortT* Abl = (ushortT*)(ws + 96 * MB);        // 16 MB
  float* sig = (float*)(ws + 112 * MB);
  double* parts = (double*)(ws + 112 * MB + 65536);
  float* meanb = (float*)(ws + 112 * MB + 131072);
  ushortT* Xlabt = (ushortT*)(ws + 113 * MB);     // 0.5 MB [128][2048]
  float* Ylab = (float*)(ws + 114 * MB);          // 1 MB
  float* Xf0 = (float*)(ws + 115 * MB);
  float* Xf1 = (float*)(ws + 116 * MB);
  ushortT* Xth0 = (ushortT*)(ws + 117 * MB);
  ushortT* Xth1 = (ushortT*)(ws + 118 * MB);

  k_normalize<<<NN, 256, 0, stream>>>(E, Enh, Enl);
  k_syrk_mfma<<<1024, 256, 0, stream>>>(Enh, Enl, A);
  k_top7<<<NN / 4, 256, 0, stream>>>(A, sig);
  k_transform<<<NN, 256, 0, stream>>>(A, sig, parts);
  k_mean<<<1, 256, 0, stream>>>(parts, meanb);
  k_thresh_bf<<<8192, 256, 0, stream>>>(A, meanb, Abh, Abl);
  k_xlabt<<<1024, 256, 0, stream>>>(labels, Xlabt);
  k_xinit<<<1024, 256, 0, stream>>>(Xf0, Xth0);
  // Ylab = (Ah+Al)[unlab, :2048] @ onehot
  k_iter<false><<<128, 512, 0, stream>>>(Abh, Abl, 0, Xlabt, nullptr, nullptr, Ylab, nullptr);
  float* xf[2] = {Xf0, Xf1};
  ushortT* xh[2] = {Xth0, Xth1};
  int cur = 0;
  for (int it = 0; it < NITER; ++it) {
    int nxt = cur ^ 1;
    k_iter<true><<<128, 512, 0, stream>>>(Abh, Abl, NLAB, xh[cur], Ylab, xf[cur],
                                          xf[nxt], xh[nxt]);
    cur = nxt;
  }
  k_output<<<1600, 256, 0, stream>>>(xf[cur], labels, out);
}

// Round 4
// 766.512 us; speedup vs baseline: 2.3398x; 1.2450x over previous
//
#include <hip/hip_runtime.h>
#include <math.h>

typedef unsigned short ushortT;
typedef __attribute__((ext_vector_type(8))) short short8;
typedef __attribute__((ext_vector_type(4))) float f32x4;

#define NN 4096
#define DD 1024
#define NC 100
#define CP 128
#define NLAB 2048
#define NITER 30

__device__ __forceinline__ ushortT bf16rn(float x) {
  unsigned u = __float_as_uint(x);
  unsigned r = (u + 0x7fffu + ((u >> 16) & 1u)) >> 16;
  return (ushortT)r;
}
__device__ __forceinline__ float bf2f(ushortT h) {
  return __uint_as_float(((unsigned)h) << 16);
}
__device__ __forceinline__ void gload16(const void* g, void* l) {
  __builtin_amdgcn_global_load_lds((const __attribute__((address_space(1))) char*)g,
                                   (__attribute__((address_space(3))) char*)l, 16, 0, 0);
}

// ---------------- normalize rows -> bf16 hi/lo splits ----------------
__global__ __launch_bounds__(256) void k_normalize(const float* __restrict__ E,
                                                   ushortT* __restrict__ Enh,
                                                   ushortT* __restrict__ Enl) {
  int row = blockIdx.x, t = threadIdx.x;
  const float4* e4 = (const float4*)(E + (size_t)row * DD);
  float4 v = e4[t];
  float ss = v.x * v.x + v.y * v.y + v.z * v.z + v.w * v.w;
  __shared__ float red[4];
  int lane = t & 63, w = t >> 6;
#pragma unroll
  for (int off = 32; off; off >>= 1) ss += __shfl_xor(ss, off);
  if (lane == 0) red[w] = ss;
  __syncthreads();
  float tot = red[0] + red[1] + red[2] + red[3];
  float d = fmaxf(sqrtf(tot), 1e-12f);
  float xs[4] = {v.x / d, v.y / d, v.z / d, v.w / d};
  ushort4 hv, lv;
  ushortT h;
  h = bf16rn(xs[0]); hv.x = h; lv.x = bf16rn(xs[0] - bf2f(h));
  h = bf16rn(xs[1]); hv.y = h; lv.y = bf16rn(xs[1] - bf2f(h));
  h = bf16rn(xs[2]); hv.z = h; lv.z = bf16rn(xs[2] - bf2f(h));
  h = bf16rn(xs[3]); hv.w = h; lv.w = bf16rn(xs[3] - bf2f(h));
  ((ushort4*)Enh)[(size_t)row * 256 + t] = hv;
  ((ushort4*)Enl)[(size_t)row * 256 + t] = lv;
}

// ---------------- A0 = relu(En@En^T) via MFMA, 3-term bf16 split; diag=1 ----------------
// Upper-triangular block grid (528) + mirrored store; 2-buf counted-vmcnt pipeline.
__global__ __launch_bounds__(256) void k_syrk_mfma(const ushortT* __restrict__ Enh,
                                                   const ushortT* __restrict__ Enl,
                                                   float* __restrict__ A) {
  __shared__ ushortT lds[2][16384];  // per buf: A-tile [128][64] @0, B-tile @8192
  int t = threadIdx.x;
  int l = t & 63, w = t >> 6;
  int rem = blockIdx.x, bi = 0;
  while (rem >= (32 - bi)) { rem -= (32 - bi); ++bi; }
  int bj = bi + rem;
  int i0 = bi << 7, j0 = bj << 7;
  int wr = w >> 1, wc = w & 1;
  f32x4 zz = {0.f, 0.f, 0.f, 0.f};
  f32x4 acc[4][4];
#pragma unroll
  for (int m = 0; m < 4; ++m)
#pragma unroll
    for (int n = 0; n < 4; ++n) acc[m][n] = zz;
  int arow_l = l & 15, kslot = l >> 4;

  auto stage = [&](int b, int s) {
    int term = s >> 4;
    int kk0 = (s & 15) << 6;
    const ushortT* sa = (term == 2) ? Enl : Enh;
    const ushortT* sb = (term == 1) ? Enl : Enh;
#pragma unroll
    for (int q = 0; q < 4; ++q) {
      int n = (q << 8) + t;
      int r = n >> 3, p = n & 7;
      int col = (p ^ (r & 7)) << 3;
      gload16(sa + (size_t)(i0 + r) * DD + kk0 + col, &lds[b][n << 3]);
      gload16(sb + (size_t)(j0 + r) * DD + kk0 + col, &lds[b][8192 + (n << 3)]);
    }
  };

  stage(0, 0);
  int cur = 0;
  for (int s = 0; s < 48; ++s) {
    if (s < 47) {
      stage(cur ^ 1, s + 1);
      asm volatile("s_waitcnt vmcnt(8)" ::: "memory");
    } else {
      asm volatile("s_waitcnt vmcnt(0)" ::: "memory");
    }
    __builtin_amdgcn_s_barrier();
#pragma unroll
    for (int kk = 0; kk < 2; ++kk) {
      int g = (kk << 2) + kslot;
      short8 av[4], bv[4];
#pragma unroll
      for (int m = 0; m < 4; ++m) {
        int r = (wr << 6) + (m << 4) + arow_l;
        av[m] = *(const short8*)&lds[cur][(r << 6) + ((g ^ (r & 7)) << 3)];
      }
#pragma unroll
      for (int n = 0; n < 4; ++n) {
        int r = (wc << 6) + (n << 4) + arow_l;
        bv[n] = *(const short8*)&lds[cur][8192 + (r << 6) + ((g ^ (r & 7)) << 3)];
      }
#pragma unroll
      for (int m = 0; m < 4; ++m)
#pragma unroll
        for (int n = 0; n < 4; ++n)
          acc[m][n] = __builtin_amdgcn_mfma_f32_16x16x32_bf16(av[m], bv[n], acc[m][n], 0, 0, 0);
    }
    asm volatile("s_waitcnt lgkmcnt(0)" ::: "memory");
    __builtin_amdgcn_s_barrier();
    cur ^= 1;
  }
  int rbase = (l >> 4) << 2;
  bool mirror = (bi != bj);
#pragma unroll
  for (int m = 0; m < 4; ++m) {
#pragma unroll
    for (int n = 0; n < 4; ++n) {
#pragma unroll
      for (int r = 0; r < 4; ++r) {
        int gi = i0 + (wr << 6) + (m << 4) + rbase + r;
        int gj = j0 + (wc << 6) + (n << 4) + (l & 15);
        float v = fmaxf(acc[m][n][r], 0.0f);
        if (gi == gj) v = 1.0f;
        A[(size_t)gi * NN + gj] = v;
        if (mirror) A[(size_t)gj * NN + gi] = v;
      }
    }
  }
}

// ---------------- sigma[i] = 7th largest of row i (float4 loads) ----------------
__device__ __forceinline__ void ins7(float (&tv)[7], float v) {
  if (v > tv[6]) {
#pragma unroll
    for (int s = 0; s < 7; s++) {
      if (v > tv[s]) { float tmp = tv[s]; tv[s] = v; v = tmp; }
    }
  }
}
__global__ __launch_bounds__(256) void k_top7(const float* __restrict__ A,
                                              float* __restrict__ sig) {
  int w = threadIdx.x >> 6, lane = threadIdx.x & 63;
  int row = (blockIdx.x << 2) + w;
  const float4* a4 = (const float4*)(A + (size_t)row * NN);
  float tv[7];
#pragma unroll
  for (int i = 0; i < 7; i++) tv[i] = -1.0f;
  for (int k = 0; k < 16; k++) {
    float4 v = a4[(k << 6) + lane];
    ins7(tv, v.x); ins7(tv, v.y); ins7(tv, v.z); ins7(tv, v.w);
  }
  int head = 0;
  float seventh = 0.0f;
  for (int r = 0; r < 7; r++) {
    float h = (head < 7) ? tv[head] : -1.0f;
    float m = h;
#pragma unroll
    for (int off = 32; off; off >>= 1) m = fmaxf(m, __shfl_xor(m, off));
    unsigned long long ball = __ballot(h == m);
    if (lane == (__ffsll(ball) - 1)) head++;
    seventh = m;
  }
  if (lane == 0) sig[row] = seventh;
}

// ---------------- transform all rows for mean; store only bottom half ----------------
__global__ __launch_bounds__(256) void k_transform(float* __restrict__ A,
                                                   const float* __restrict__ sig,
                                                   double* __restrict__ parts) {
  int row = blockIdx.x;
  float si = sig[row];
  float4* a4 = (float4*)(A + (size_t)row * NN);
  const float4* s4 = (const float4*)sig;
  int t = threadIdx.x;
  bool store = (row >= NLAB);
  double local = 0.0;
#pragma unroll
  for (int k = 0; k < 4; k++) {
    int j = (k << 8) + t;
    float4 v = a4[j];
    float4 sg = s4[j];
    float4 ww;
    ww.x = expf(-(v.x * v.x) / (si * sg.x));
    ww.y = expf(-(v.y * v.y) / (si * sg.y));
    ww.z = expf(-(v.z * v.z) / (si * sg.z));
    ww.w = expf(-(v.w * v.w) / (si * sg.w));
    if (store) a4[j] = ww;
    local += (double)ww.x + (double)ww.y + (double)ww.z + (double)ww.w;
  }
  __shared__ double dred[4];
  int lane = t & 63, wv = t >> 6;
#pragma unroll
  for (int off = 32; off; off >>= 1) local += __shfl_xor(local, off);
  if (lane == 0) dred[wv] = local;
  __syncthreads();
  if (t == 0) parts[row] = dred[0] + dred[1] + dred[2] + dred[3];
}

__global__ __launch_bounds__(256) void k_mean(const double* __restrict__ parts,
                                              float* __restrict__ meanb) {
  int t = threadIdx.x;
  double local = 0.0;
#pragma unroll
  for (int k = 0; k < NN / 256; k++) local += parts[(k << 8) + t];
  __shared__ double dred[4];
  int lane = t & 63, wv = t >> 6;
#pragma unroll
  for (int off = 32; off; off >>= 1) local += __shfl_xor(local, off);
  if (lane == 0) dred[wv] = local;
  __syncthreads();
  if (t == 0) meanb[0] = (float)((dred[0] + dred[1] + dred[2] + dred[3]) / ((double)NN * (double)NN));
}

// ---------------- threshold bottom half + bf16 hi/lo split ----------------
__global__ __launch_bounds__(256) void k_thresh_bf(const float* __restrict__ A,
                                                   const float* __restrict__ meanb,
                                                   ushortT* __restrict__ Abh,
                                                   ushortT* __restrict__ Abl) {
  float m = meanb[0];
  size_t i4 = ((size_t)blockIdx.x << 8) + threadIdx.x;  // over 2048*4096/4
  float4 v = ((const float4*)(A + (size_t)NLAB * NN))[i4];
  float c0 = (v.x < m) ? 0.0f : v.x;
  float c1 = (v.y < m) ? 0.0f : v.y;
  float c2 = (v.z < m) ? 0.0f : v.z;
  float c3 = (v.w < m) ? 0.0f : v.w;
  ushort4 hv, lv;
  ushortT h;
  h = bf16rn(c0); hv.x = h; lv.x = bf16rn(c0 - bf2f(h));
  h = bf16rn(c1); hv.y = h; lv.y = bf16rn(c1 - bf2f(h));
  h = bf16rn(c2); hv.z = h; lv.z = bf16rn(c2 - bf2f(h));
  h = bf16rn(c3); hv.w = h; lv.w = bf16rn(c3 - bf2f(h));
  ((ushort4*)Abh)[i4] = hv;
  ((ushort4*)Abl)[i4] = lv;
}

// ---------------- one-hot labels, transposed bf16 [128][2048] ----------------
__global__ __launch_bounds__(256) void k_xlabt(const int* __restrict__ labels,
                                               ushortT* __restrict__ Xlabt) {
  int idx = (blockIdx.x << 8) + threadIdx.x;  // 262144
  int c = idx >> 11, j = idx & 2047;
  Xlabt[idx] = (labels[j] == c) ? (ushortT)0x3F80 : (ushortT)0;
}

// ---------------- X init: fp32 [2048][128] + transposed bf16 ----------------
__global__ __launch_bounds__(256) void k_xinit(float* __restrict__ Xf,
                                               ushortT* __restrict__ Xth) {
  int idx = (blockIdx.x << 8) + threadIdx.x;  // 262144 over [2048][128]
  int i = idx >> 7, c = idx & 127;
  float v = (c < NC) ? 0.01f : 0.0f;
  Xf[idx] = v;
  Xth[(size_t)c * NLAB + i] = bf16rn(v);
}

// ---------------- iterA: mm partial GEMM, 16 rows x 32 cols per block, K=2048 ----
// 512 blocks = 128 row-groups x 4 col-pairs; XCD-pinned (bid&7 -> row range).
__global__ __launch_bounds__(512) void k_iterA(
    const ushortT* __restrict__ Ah, const ushortT* __restrict__ Al, int acol0,
    const ushortT* __restrict__ Xt,  // [128][2048] bf16 transposed
    float* __restrict__ mm) {
  __shared__ float red[8 * 32 * 20];  // [wave][col32][row16 pad20] = 20 KB
  int t = threadIdx.x, l = t & 63, w = t >> 6;
  int bid = blockIdx.x;
  int x = bid & 7, cp = (bid >> 3) & 3, q = bid >> 5;
  int rg = (x << 4) + q;
  int brow0 = rg << 4;
  int arow = l & 15, khi = l >> 4;
  int kb = w << 8;  // wave K-slice (256)
  f32x4 acc[2];
  acc[0] = (f32x4){0.f, 0.f, 0.f, 0.f};
  acc[1] = (f32x4){0.f, 0.f, 0.f, 0.f};
  const ushortT* aph = Ah + (size_t)(brow0 + arow) * NN + acol0 + kb + (khi << 3);
  const ushortT* apl = Al + (size_t)(brow0 + arow) * NN + acol0 + kb + (khi << 3);
  const ushortT* xp = Xt + (size_t)((cp << 5) + arow) * NLAB + kb + (khi << 3);
#pragma unroll
  for (int g = 0; g < 8; ++g) {
    short8 ahv = *(const short8*)(aph + (g << 5));
    short8 alv = *(const short8*)(apl + (g << 5));
#pragma unroll
    for (int n = 0; n < 2; ++n) {
      short8 bv = *(const short8*)(xp + ((size_t)(n << 4)) * NLAB + (g << 5));
      acc[n] = __builtin_amdgcn_mfma_f32_16x16x32_bf16(ahv, bv, acc[n], 0, 0, 0);
      acc[n] = __builtin_amdgcn_mfma_f32_16x16x32_bf16(alv, bv, acc[n], 0, 0, 0);
    }
  }
  int rbase = khi << 2;
#pragma unroll
  for (int n = 0; n < 2; ++n)
    *(f32x4*)&red[((w << 5) + (n << 4) + arow) * 20 + rbase] = acc[n];
  __syncthreads();
  int row = t >> 5, col = t & 31;
  float s = 0.f;
#pragma unroll
  for (int w2 = 0; w2 < 8; ++w2) s += red[((w2 << 5) + col) * 20 + row];
  mm[(size_t)(brow0 + row) * CP + (cp << 5) + col] = s;
}

// ---------------- iterB: mult = x*(1+mm+yl); rowsum; normalize; write fp32+bf16T ----
__global__ __launch_bounds__(256) void k_iterB(
    const float* __restrict__ mm, const float* __restrict__ Ylab,
    const float* __restrict__ Xprev, float* __restrict__ outF,
    ushortT* __restrict__ outTh) {
  int bb = blockIdx.x;  // 256 blocks, XCD-pinned
  int x = bb & 7, q = bb >> 3;
  int brow = ((x << 5) + q) << 3;  // 8 rows per block
  int t = threadIdx.x, l = t & 63, w = t >> 6;
  int row = brow + (w << 1) + (l >> 5);
  int c4 = (l & 31) << 2;
  size_t o = (size_t)row * CP + c4;
  float4 m4 = *(const float4*)&mm[o];
  float4 yl = *(const float4*)&Ylab[o];
  float4 xv = *(const float4*)&Xprev[o];
  float mult[4];
  mult[0] = fmaf(xv.x, m4.x + yl.x, xv.x);
  mult[1] = fmaf(xv.y, m4.y + yl.y, xv.y);
  mult[2] = fmaf(xv.z, m4.z + yl.z, xv.z);
  mult[3] = fmaf(xv.w, m4.w + yl.w, xv.w);
  float s = mult[0] + mult[1] + mult[2] + mult[3];
#pragma unroll
  for (int off = 16; off; off >>= 1) s += __shfl_xor(s, off);
  float denom = s + 1e-8f;
  float4 ov;
  ov.x = mult[0] / denom; ov.y = mult[1] / denom;
  ov.z = mult[2] / denom; ov.w = mult[3] / denom;
  *(float4*)&outF[o] = ov;
  outTh[(size_t)(c4 + 0) * NLAB + row] = bf16rn(ov.x);
  outTh[(size_t)(c4 + 1) * NLAB + row] = bf16rn(ov.y);
  outTh[(size_t)(c4 + 2) * NLAB + row] = bf16rn(ov.z);
  outTh[(size_t)(c4 + 3) * NLAB + row] = bf16rn(ov.w);
}

// ---------------- output assembly ----------------
__global__ __launch_bounds__(256) void k_output(const float* __restrict__ Xf,
                                                const int* __restrict__ labels,
                                                float* __restrict__ out) {
  int idx = (blockIdx.x << 8) + threadIdx.x;  // 409600
  int i = idx / NC, c = idx - i * NC;
  float v;
  if (i < NLAB) v = (labels[i] == c) ? 1.0f : 0.0f;
  else v = Xf[((size_t)(i - NLAB) << 7) + c];
  out[idx] = v;
}

extern "C" void kernel_launch(void* const* d_in, const int* in_sizes, int n_in,
                              void* d_out, int out_size, void* d_ws, size_t ws_size,
                              hipStream_t stream) {
  const float* E = (const float*)d_in[0];
  const int* labels = (const int*)d_in[1];
  float* out = (float*)d_out;
  char* ws = (char*)d_ws;
  const size_t MB = 1024 * 1024;

  float* A = (float*)ws;                          // 64 MB (dead after thresh_bf)
  float* mmbuf = (float*)ws;                      // 1 MB, overlays dead A
  ushortT* Enh = (ushortT*)(ws + 64 * MB);        // 8 MB
  ushortT* Enl = (ushortT*)(ws + 72 * MB);        // 8 MB
  ushortT* Abh = (ushortT*)(ws + 80 * MB);        // 16 MB [2048][4096] bf16
  ushortT* Abl = (ushortT*)(ws + 96 * MB);        // 16 MB
  float* sig = (float*)(ws + 112 * MB);
  double* parts = (double*)(ws + 112 * MB + 65536);
  float* meanb = (float*)(ws + 112 * MB + 131072);
  ushortT* Xlabt = (ushortT*)(ws + 113 * MB);     // 0.5 MB [128][2048]
  float* Ylab = (float*)(ws + 114 * MB);          // 1 MB
  float* Xf0 = (float*)(ws + 115 * MB);
  float* Xf1 = (float*)(ws + 116 * MB);
  ushortT* Xth0 = (ushortT*)(ws + 117 * MB);
  ushortT* Xth1 = (ushortT*)(ws + 118 * MB);

  k_normalize<<<NN, 256, 0, stream>>>(E, Enh, Enl);
  k_syrk_mfma<<<528, 256, 0, stream>>>(Enh, Enl, A);
  k_top7<<<NN / 4, 256, 0, stream>>>(A, sig);
  k_transform<<<NN, 256, 0, stream>>>(A, sig, parts);
  k_mean<<<1, 256, 0, stream>>>(parts, meanb);
  k_thresh_bf<<<8192, 256, 0, stream>>>(A, meanb, Abh, Abl);
  k_xlabt<<<1024, 256, 0, stream>>>(labels, Xlabt);
  k_xinit<<<1024, 256, 0, stream>>>(Xf0, Xth0);
  // Ylab = (Ah+Al)[unlab, :2048] @ onehot
  k_iterA<<<512, 512, 0, stream>>>(Abh, Abl, 0, Xlabt, Ylab);
  float* xf[2] = {Xf0, Xf1};
  ushortT* xh[2] = {Xth0, Xth1};
  int cur = 0;
  for (int it = 0; it < NITER; ++it) {
    int nxt = cur ^ 1;
    k_iterA<<<512, 512, 0, stream>>>(Abh, Abl, NLAB, xh[cur], mmbuf);
    k_iterB<<<256, 256, 0, stream>>>(mmbuf, Ylab, xf[cur], xf[nxt], xh[nxt]);
    cur = nxt;
  }
  k_output<<<1600, 256, 0, stream>>>(xf[cur], labels, out);
}